// Round 3
// baseline (255.465 us; speedup 1.0000x reference)
//
#include <hip/hip_runtime.h>

// VectorQuantizer: B=32,D=64,H=64,W=64 -> N=131072 px; K=512 codes.
// out[0] = 1.25*mean((E[idx]-z)^2); out[1..] = Zq as [B,D,H,W].
// R2: wave-independent design. Each wave owns 32 pixels and loops over ALL
// 512 codes (32 MFMA code-tiles, B streamed from L2-hot E16). Argmin merge is
// lane-local + shfl across the 16 column-lanes only -> no cross-wave barriers
// on the hot path. 4096 waves (1024 blocks) for 16 waves/CU.

typedef __bf16 bf16x8 __attribute__((ext_vector_type(8)));
typedef __bf16 bf16x4 __attribute__((ext_vector_type(4)));
typedef float  f32x4  __attribute__((ext_vector_type(4)));

#define LOSS_SCALE (1.25f / 8388608.f)   // 1.25 / (N*D)

// ws: [0,64K) E16 bf16[512][64]; [64K,+2K) en2=|e|^2+2; [67584,+512) loss cells;
//     [68096] done-counter
__global__ __launch_bounds__(256) void vq_prep(const float* __restrict__ E,
                                               __bf16* __restrict__ E16,
                                               float* __restrict__ en2,
                                               float* __restrict__ cells,
                                               int* __restrict__ counter) {
  int g = blockIdx.x * 256 + threadIdx.x;          // 8192 thr, one float4 each
  if (blockIdx.x == 0) {
    if (threadIdx.x < 128) cells[threadIdx.x] = 0.f;
    if (threadIdx.x == 128) *counter = 0;
  }
  float4 v = ((const float4*)E)[g];
  float ss = v.x*v.x + v.y*v.y + v.z*v.z + v.w*v.w;
  #pragma unroll
  for (int off = 1; off < 16; off <<= 1) ss += __shfl_xor(ss, off);
  if ((g & 15) == 0) en2[g >> 4] = ss + 2.0f;      // +2: positive-key bias
  bf16x4 b;
  b[0] = (__bf16)v.x; b[1] = (__bf16)v.y; b[2] = (__bf16)v.z; b[3] = (__bf16)v.w;
  ((bf16x4*)E16)[g] = b;
}

#define CT_STEP(CT, B0_, B1_, EN_) do {                                        \
    unsigned cvec = ((unsigned)((CT) << 4)) | (unsigned)m16;                   \
    _Pragma("unroll")                                                          \
    for (int pt = 0; pt < 2; ++pt) {                                           \
      f32x4 acc = {0.f, 0.f, 0.f, 0.f};                                        \
      acc = __builtin_amdgcn_mfma_f32_16x16x32_bf16(A[pt][0], B0_, acc, 0,0,0);\
      acc = __builtin_amdgcn_mfma_f32_16x16x32_bf16(A[pt][1], B1_, acc, 0,0,0);\
      _Pragma("unroll")                                                        \
      for (int r = 0; r < 4; ++r) {                                            \
        float d2 = fmaf(-2.f, acc[r], EN_);       /* dist+2 in [1,3) */        \
        unsigned key = (__float_as_uint(d2) & 0xFFFFFE00u) | cvec;             \
        if (key < mnk[pt][r]) mnk[pt][r] = key;                                \
      }                                                                        \
    }                                                                          \
  } while (0)

__global__ __launch_bounds__(256, 4) void vq_main(const float* __restrict__ in,
                                                  const float* __restrict__ E,
                                                  const __bf16* __restrict__ E16,
                                                  const float* __restrict__ en2,
                                                  float* __restrict__ out,
                                                  float* __restrict__ cells,
                                                  int* __restrict__ counter) {
  __shared__ __bf16 Zl[4][32 * 72];      // per-wave 32px x 64d, rows padded to 72
  __shared__ int    idx_l[4][32];
  __shared__ int    amlast;

  const int t = threadIdx.x, lane = t & 63, w = t >> 6;
  const int m16 = lane & 15, q = lane >> 4;
  const int g = blockIdx.x * 4 + w;                 // wave tile 0..4095 (32 px)
  const int base = (g >> 7) * 262144 + ((g & 127) << 5);

  float loss_acc = 0.f;

  // ---- stage: lane loads float2 (px = 2*m16, 2*m16+1) at d = q*16 + j ------
  {
    bf16x8 vv[4];
    const float* p = in + base + (q * 16) * 4096 + 2 * m16;
    #pragma unroll
    for (int j = 0; j < 16; ++j) {
      float2 xy = *(const float2*)(p + j * 4096);
      loss_acc += xy.x * xy.x + xy.y * xy.y;        // |z|^2 folded into loss
      vv[j >> 3][j & 7]       = (__bf16)xy.x;
      vv[2 + (j >> 3)][j & 7] = (__bf16)xy.y;
    }
    __bf16* row0 = &Zl[w][(2 * m16) * 72 + q * 16];
    __bf16* row1 = &Zl[w][(2 * m16 + 1) * 72 + q * 16];
    *(bf16x8*)row0 = vv[0]; *(bf16x8*)(row0 + 8) = vv[1];
    *(bf16x8*)row1 = vv[2]; *(bf16x8*)(row1 + 8) = vv[3];
  }
  __syncthreads();

  // ---- A fragments: 2 sub-tiles of 16 px, 2 k-halves -----------------------
  bf16x8 A[2][2];
  #pragma unroll
  for (int pt = 0; pt < 2; ++pt) {
    A[pt][0] = *(const bf16x8*)&Zl[w][(pt * 16 + m16) * 72 + q * 8];
    A[pt][1] = *(const bf16x8*)&Zl[w][(pt * 16 + m16) * 72 + 32 + q * 8];
  }

  unsigned mnk[2][4];
  #pragma unroll
  for (int pt = 0; pt < 2; ++pt)
    #pragma unroll
    for (int r = 0; r < 4; ++r) mnk[pt][r] = 0xFFFFFFFFu;

  // ---- loop over all 512 codes: 32 tiles, 1-deep B prefetch ----------------
  const __bf16* Eb = E16 + m16 * 64 + q * 8;
  bf16x8 B0 = *(const bf16x8*)Eb;
  bf16x8 B1 = *(const bf16x8*)(Eb + 32);
  float  en = en2[m16];
  #pragma unroll 4
  for (int ct = 0; ct < 31; ++ct) {
    const __bf16* nb = Eb + (ct + 1) * 1024;
    bf16x8 nB0 = *(const bf16x8*)nb;
    bf16x8 nB1 = *(const bf16x8*)(nb + 32);
    float  nen = en2[(ct + 1) * 16 + m16];
    CT_STEP(ct, B0, B1, en);
    B0 = nB0; B1 = nB1; en = nen;
  }
  CT_STEP(31, B0, B1, en);

  // ---- merge across the 16 column-lanes (codes); rows are pixels -----------
  #pragma unroll
  for (int pt = 0; pt < 2; ++pt)
    #pragma unroll
    for (int r = 0; r < 4; ++r) {
      unsigned key = mnk[pt][r];
      #pragma unroll
      for (int off = 1; off < 16; off <<= 1) {
        unsigned o = (unsigned)__shfl_xor((int)key, off);
        key = o < key ? o : key;
      }
      mnk[pt][r] = key;
    }
  if (m16 == 0) {                       // holder lanes: px = pt*16 + q*4 + r
    #pragma unroll
    for (int pt = 0; pt < 2; ++pt)
      #pragma unroll
      for (int r = 0; r < 4; ++r) {
        idx_l[w][pt * 16 + q * 4 + r] = (int)(mnk[pt][r] & 511u);
        loss_acc += __uint_as_float(mnk[pt][r]) - 2.0f;   // dist (idx-bit noise ~1e-4)
      }
  }
  __syncthreads();

  // ---- gather E[idx] fp32, write Zq: lane -> (px = lane>>1, part = lane&1) -
  {
    int px = lane >> 1, part = lane & 1;
    int row = idx_l[w][px];
    const float4* Er = (const float4*)(E + row * 64 + part * 32);
    float* op = out + 1 + base + part * 32 * 4096 + px;
    #pragma unroll
    for (int k = 0; k < 8; ++k) {
      float4 v = Er[k];
      op[(k * 4 + 0) * 4096] = v.x;
      op[(k * 4 + 1) * 4096] = v.y;
      op[(k * 4 + 2) * 4096] = v.z;
      op[(k * 4 + 3) * 4096] = v.w;
    }
  }

  // ---- loss: per-wave reduce -> spread cells; last block finalizes ---------
  #pragma unroll
  for (int off = 1; off < 64; off <<= 1) loss_acc += __shfl_xor(loss_acc, off);
  if (lane == 0) atomicAdd(&cells[blockIdx.x & 127], loss_acc);
  __threadfence();
  __syncthreads();
  if (t == 0) amlast = (atomicAdd(counter, 1) == 1023) ? 1 : 0;
  __syncthreads();
  if (amlast && t < 64) {
    __threadfence();
    float s = atomicAdd(&cells[t], 0.f) + atomicAdd(&cells[t + 64], 0.f);
    #pragma unroll
    for (int off = 1; off < 64; off <<= 1) s += __shfl_xor(s, off);
    if (t == 0) out[0] = s * LOSS_SCALE;
  }
}

extern "C" void kernel_launch(void* const* d_in, const int* in_sizes, int n_in,
                              void* d_out, int out_size, void* d_ws, size_t ws_size,
                              hipStream_t stream) {
  (void)in_sizes; (void)n_in; (void)out_size; (void)ws_size;
  const float* in = (const float*)d_in[0];   // [32,64,64,64]
  const float* E  = (const float*)d_in[1];   // [512,64]
  float* out = (float*)d_out;                // [1 + 8388608]
  __bf16* E16    = (__bf16*)d_ws;
  float*  en2    = (float*)((char*)d_ws + 65536);
  float*  cells  = (float*)((char*)d_ws + 67584);
  int*    counter= (int*)((char*)d_ws + 68096);

  vq_prep<<<32, 256, 0, stream>>>(E, E16, en2, cells, counter);
  vq_main<<<1024, 256, 0, stream>>>(in, E, E16, en2, out, cells, counter);
}

// Round 4
// 140.591 us; speedup vs baseline: 1.8171x; 1.8171x over previous
//
#include <hip/hip_runtime.h>

// VectorQuantizer: B=32,D=64,H=64,W=64 -> N=131072 px; K=512 codes.
// out[0] = 1.25*mean((E[idx]-z)^2); out[1..] = Zq as [B,D,H,W].
// R3: R1 structure (wave owns 128 codes in regs; 64-px tile; cross-wave merge
// in LDS) but ONE tile per block x 2048 blocks (block churn hides store/load
// latency; stores fire-and-forget at block end). Argmin cost cut to 2 VALU/elem
// by passing en2=|e|^2+2 as the MFMA C operand with Z pre-scaled by -2 (d2 =
// en2 - 2 z.e in (1,3) > 0 => raw-bit uint min works; low 9 bits carry idx).
// Loss: per-block partial -> cells, tiny second kernel reduces (no atomics).

typedef __bf16 bf16x8 __attribute__((ext_vector_type(8)));
typedef float  f32x4  __attribute__((ext_vector_type(4)));
typedef float  f32x4u __attribute__((ext_vector_type(4), aligned(4)));

#define LOSS_SCALE (1.25f / 8388608.f)   // 1.25 / (N*D)

__global__ __launch_bounds__(256, 2) void vq_main(const float* __restrict__ in,
                                                  const float* __restrict__ E,
                                                  float* __restrict__ out,
                                                  float* __restrict__ cells) {
  __shared__ __bf16 Zl[64 * 72];          // 64 px x 64 d (scaled by -2), pad 72
  __shared__ float  znp[4 * 64];          // per-(wave,px) |z|^2 partials
  __shared__ unsigned keys[4 * 64];       // per-(wave,px) packed (d2|idx)

  const int t = threadIdx.x, lane = t & 63, w = t >> 6;
  const int m16 = lane & 15, q = lane >> 4;
  const int base = (blockIdx.x >> 6) * 262144 + ((blockIdx.x & 63) << 6);

  // ---- B-prep: wave w owns codes [w*128,(w+1)*128) as reg fragments --------
  bf16x8 B0s[8], B1s[8];
  float  en[8];                           // |e|^2 + 2 per code column
  const int cbase = w * 128 + m16;
  #pragma unroll
  for (int ct = 0; ct < 8; ++ct) {
    int c = cbase + ct * 16;
    const float4* Ea = (const float4*)(E + c * 64 + q * 8);
    const float4* Eb = (const float4*)(E + c * 64 + 32 + q * 8);
    float4 a0 = Ea[0], a1 = Ea[1], b0 = Eb[0], b1 = Eb[1];
    float f0[8] = {a0.x,a0.y,a0.z,a0.w,a1.x,a1.y,a1.z,a1.w};
    float f1[8] = {b0.x,b0.y,b0.z,b0.w,b1.x,b1.y,b1.z,b1.w};
    float ss = 0.f;
    bf16x8 v0, v1;
    #pragma unroll
    for (int j = 0; j < 8; ++j) {
      ss += f0[j]*f0[j] + f1[j]*f1[j];
      v0[j] = (__bf16)f0[j];
      v1[j] = (__bf16)f1[j];
    }
    ss += __shfl_xor(ss, 16);             // sum over the 4 q-lanes
    ss += __shfl_xor(ss, 32);
    en[ct] = ss + 2.0f;
    B0s[ct] = v0; B1s[ct] = v1;
  }

  // ---- stage Z tile (scaled by -2): px = lane, wave w loads 16 d-rows ------
  {
    float f0[8], f1[8], ss = 0.f;
    #pragma unroll
    for (int j = 0; j < 8; ++j) {
      f0[j] = in[base + (w * 8 + j) * 4096 + lane];
      f1[j] = in[base + ((w + 4) * 8 + j) * 4096 + lane];
    }
    bf16x8 v0, v1;
    #pragma unroll
    for (int j = 0; j < 8; ++j) {
      ss += f0[j]*f0[j] + f1[j]*f1[j];
      v0[j] = (__bf16)(-2.f * f0[j]);
      v1[j] = (__bf16)(-2.f * f1[j]);
    }
    *(bf16x8*)&Zl[lane * 72 + w * 8]      = v0;
    *(bf16x8*)&Zl[lane * 72 + 32 + w * 8] = v1;
    znp[w * 64 + lane] = ss;
  }
  __syncthreads();

  // ---- A fragments: 4 px sub-tiles x 2 k-halves ----------------------------
  bf16x8 A[4][2];
  #pragma unroll
  for (int pt = 0; pt < 4; ++pt) {
    A[pt][0] = *(const bf16x8*)&Zl[(pt * 16 + m16) * 72 + q * 8];
    A[pt][1] = *(const bf16x8*)&Zl[(pt * 16 + m16) * 72 + 32 + q * 8];
  }

  unsigned mnk[4][4];
  #pragma unroll
  for (int pt = 0; pt < 4; ++pt)
    #pragma unroll
    for (int r = 0; r < 4; ++r) mnk[pt][r] = 0xFFFFFFFFu;

  #pragma unroll
  for (int ct = 0; ct < 8; ++ct) {
    f32x4 einit = {en[ct], en[ct], en[ct], en[ct]};
    const unsigned c = (unsigned)(cbase + ct * 16);
    #pragma unroll
    for (int pt = 0; pt < 4; ++pt) {
      // d2 = en2 + (-2z).e  in (1,3): positive => raw bits are order-monotone
      f32x4 acc = __builtin_amdgcn_mfma_f32_16x16x32_bf16(A[pt][0], B0s[ct], einit, 0, 0, 0);
      acc = __builtin_amdgcn_mfma_f32_16x16x32_bf16(A[pt][1], B1s[ct], acc, 0, 0, 0);
      #pragma unroll
      for (int r = 0; r < 4; ++r) {
        unsigned key = (__float_as_uint(acc[r]) & 0xFFFFFE00u) | c;
        if (key < mnk[pt][r]) mnk[pt][r] = key;
      }
    }
  }

  // ---- merge across the 16 code-column lanes; write per-wave winners -------
  #pragma unroll
  for (int pt = 0; pt < 4; ++pt)
    #pragma unroll
    for (int r = 0; r < 4; ++r) {
      unsigned key = mnk[pt][r];
      #pragma unroll
      for (int off = 1; off < 16; off <<= 1) {
        unsigned o = (unsigned)__shfl_xor((int)key, off);
        key = o < key ? o : key;
      }
      if (m16 == 0) keys[w * 64 + pt * 16 + q * 4 + r] = key;
    }
  __syncthreads();

  // ---- loss partial (wave 0): per-px min over waves + |z|^2, block sum -----
  if (t < 64) {
    unsigned k0 = keys[t], k1 = keys[64 + t], k2 = keys[128 + t], k3 = keys[192 + t];
    unsigned km = k1 < k0 ? k1 : k0;
    unsigned kn = k3 < k2 ? k3 : k2;
    km = kn < km ? kn : km;
    float zn = znp[t] + znp[64 + t] + znp[128 + t] + znp[192 + t];
    float md = zn + (__uint_as_float(km) - 2.0f);   // min_k ||z-e_k||^2
    #pragma unroll
    for (int off = 1; off < 64; off <<= 1) md += __shfl_xor(md, off);
    if (t == 0) cells[blockIdx.x] = md;
  }

  // ---- gather + vectorized store: thread t -> px4=(t&15)*4, d=t>>4 (+16j) --
  {
    int px4 = (t & 15) * 4, d0 = t >> 4;
    unsigned a0 = keys[px4],     b0_ = keys[64 + px4],     c0 = keys[128 + px4],     e0k = keys[192 + px4];
    unsigned a1 = keys[px4 + 1], b1_ = keys[64 + px4 + 1], c1 = keys[128 + px4 + 1], e1k = keys[192 + px4 + 1];
    unsigned a2 = keys[px4 + 2], b2_ = keys[64 + px4 + 2], c2 = keys[128 + px4 + 2], e2k = keys[192 + px4 + 2];
    unsigned a3 = keys[px4 + 3], b3_ = keys[64 + px4 + 3], c3 = keys[128 + px4 + 3], e3k = keys[192 + px4 + 3];
    unsigned m0 = min(min(a0, b0_), min(c0, e0k));
    unsigned m1 = min(min(a1, b1_), min(c1, e1k));
    unsigned m2 = min(min(a2, b2_), min(c2, e2k));
    unsigned m3 = min(min(a3, b3_), min(c3, e3k));
    const float* e0 = E + (m0 & 511u) * 64;
    const float* e1 = E + (m1 & 511u) * 64;
    const float* e2 = E + (m2 & 511u) * 64;
    const float* e3 = E + (m3 & 511u) * 64;
    float* op = out + 1 + base + px4;
    #pragma unroll
    for (int j = 0; j < 4; ++j) {
      int d = d0 + 16 * j;
      f32x4u v;
      v[0] = e0[d]; v[1] = e1[d]; v[2] = e2[d]; v[3] = e3[d];
      *(f32x4u*)(op + d * 4096) = v;
    }
  }
}

// ---- tiny reduce: sum 2048 block partials -> out[0] ------------------------
__global__ __launch_bounds__(256) void vq_loss(const float* __restrict__ cells,
                                               float* __restrict__ out) {
  __shared__ float wsum[4];
  int t = threadIdx.x;
  const float4* c4 = (const float4*)cells;       // 512 float4
  float s = 0.f;
  #pragma unroll
  for (int j = 0; j < 2; ++j) {
    float4 v = c4[t + 256 * j];
    s += v.x + v.y + v.z + v.w;
  }
  #pragma unroll
  for (int off = 1; off < 64; off <<= 1) s += __shfl_xor(s, off);
  if ((t & 63) == 0) wsum[t >> 6] = s;
  __syncthreads();
  if (t == 0) out[0] = (wsum[0] + wsum[1] + wsum[2] + wsum[3]) * LOSS_SCALE;
}

extern "C" void kernel_launch(void* const* d_in, const int* in_sizes, int n_in,
                              void* d_out, int out_size, void* d_ws, size_t ws_size,
                              hipStream_t stream) {
  (void)in_sizes; (void)n_in; (void)out_size; (void)ws_size;
  const float* in = (const float*)d_in[0];   // [32,64,64,64]
  const float* E  = (const float*)d_in[1];   // [512,64]
  float* out   = (float*)d_out;              // [1 + 8388608]
  float* cells = (float*)d_ws;               // 2048 floats

  vq_main<<<2048, 256, 0, stream>>>(in, E, out, cells);
  vq_loss<<<1, 256, 0, stream>>>(cells, out);
}

// Round 5
// 128.994 us; speedup vs baseline: 1.9804x; 1.0899x over previous
//
#include <hip/hip_runtime.h>

// VectorQuantizer: B=32,D=64,H=64,W=64 -> N=131072 px; K=512 codes.
// out[0] = 1.25*mean((E[idx]-z)^2); out[1..] = Zq as [B,D,H,W].
// R4: fully wave-independent, ZERO __syncthreads. 4096 waves x 32px tiles
// (16 waves/CU resident). Per wave: stage Z (scaled -2, bf16) into private LDS
// slice -> A-frags; stream all 512 codes (32 tiles) from L2-hot E16 with
// 1-deep prefetch; dist = en2 + (-2z).e via MFMA C-operand, in (1,3) so raw
// uint bits are order-monotone (low 9 bits carry code idx); merge across the
// 16 column-lanes only. Loss -> cells, reduced by a tiny kernel. All hot-loop
// state in NAMED registers (R2's scratch-spill lesson).

typedef __bf16 bf16x8 __attribute__((ext_vector_type(8)));
typedef __bf16 bf16x4 __attribute__((ext_vector_type(4)));
typedef float  f32x4  __attribute__((ext_vector_type(4)));
typedef int    i32x4  __attribute__((ext_vector_type(4)));
typedef float  f32x2u __attribute__((ext_vector_type(2), aligned(4)));

#define LOSS_SCALE (1.25f / 8388608.f)   // 1.25 / (N*D)

// ---- prep: E fp32 -> E16 bf16 (row-major), en2 = |e|^2 + 2 -----------------
__global__ __launch_bounds__(256) void vq_prep(const float* __restrict__ E,
                                               __bf16* __restrict__ E16,
                                               float* __restrict__ en2) {
  int g = blockIdx.x * 256 + threadIdx.x;          // 8192 thr, one float4 each
  float4 v = ((const float4*)E)[g];
  float ss = v.x*v.x + v.y*v.y + v.z*v.z + v.w*v.w;
  #pragma unroll
  for (int off = 1; off < 16; off <<= 1) ss += __shfl_xor(ss, off);
  if ((g & 15) == 0) en2[g >> 4] = ss + 2.0f;
  bf16x4 b;
  b[0] = (__bf16)v.x; b[1] = (__bf16)v.y; b[2] = (__bf16)v.z; b[3] = (__bf16)v.w;
  ((bf16x4*)E16)[g] = b;
}

#define ARGMIN(KK, RV) { unsigned key_ = (__float_as_uint(RV) & 0xFFFFFE00u) | cvec; \
                         if (key_ < KK) KK = key_; }
#define MERGE16(KK) { unsigned o_; \
    o_ = __shfl_xor(KK, 1); if (o_ < KK) KK = o_; \
    o_ = __shfl_xor(KK, 2); if (o_ < KK) KK = o_; \
    o_ = __shfl_xor(KK, 4); if (o_ < KK) KK = o_; \
    o_ = __shfl_xor(KK, 8); if (o_ < KK) KK = o_; }

__global__ __launch_bounds__(256, 4) void vq_main(const float* __restrict__ in,
                                                  const float* __restrict__ E,
                                                  const __bf16* __restrict__ E16,
                                                  const float* __restrict__ en2,
                                                  float* __restrict__ out,
                                                  float* __restrict__ cells) {
  __shared__ __bf16 Zl[4][32 * 72];       // per-wave slice: 32 px x 64 d, pad 72
  __shared__ int    idxl[4][32];          // per-wave winner codes

  const int t = threadIdx.x, lane = t & 63, w = t >> 6;
  const int q = lane >> 4, m = lane & 15;
  const int g = blockIdx.x * 4 + w;                 // wave tile 0..4095 (32 px)
  const int base = (g >> 7) * 262144 + ((g & 127) << 5);

  // ---- stage: lane loads 16 float2 (px 2m,2m+1) at d = q*16+j --------------
  float zn = 0.f;
  {
    float2 L[16];
    const float* p = in + base + (q * 16) * 4096 + 2 * m;
    #pragma unroll
    for (int j = 0; j < 16; ++j) L[j] = *(const float2*)(p + j * 4096);
    bf16x8 c00, c01, c10, c11;
    #pragma unroll
    for (int j = 0; j < 8; ++j) {
      c00[j] = (__bf16)(-2.f * L[j].x);
      c10[j] = (__bf16)(-2.f * L[j].y);
      c01[j] = (__bf16)(-2.f * L[j + 8].x);
      c11[j] = (__bf16)(-2.f * L[j + 8].y);
    }
    #pragma unroll
    for (int j = 0; j < 16; ++j) zn += L[j].x * L[j].x + L[j].y * L[j].y;
    __bf16* r0 = &Zl[w][(2 * m) * 72 + q * 16];
    __bf16* r1 = &Zl[w][(2 * m + 1) * 72 + q * 16];
    *(bf16x8*)r0 = c00; *(bf16x8*)(r0 + 8) = c01;
    *(bf16x8*)r1 = c10; *(bf16x8*)(r1 + 8) = c11;
  }
  __threadfence_block();                  // wave-local LDS visibility, no barrier

  // ---- A fragments: pt 0/1 -> px = pt*16 + m, k-halves q*8 / 32+q*8 --------
  bf16x8 A00 = *(const bf16x8*)&Zl[w][(m) * 72 + q * 8];
  bf16x8 A01 = *(const bf16x8*)&Zl[w][(m) * 72 + 32 + q * 8];
  bf16x8 A10 = *(const bf16x8*)&Zl[w][(16 + m) * 72 + q * 8];
  bf16x8 A11 = *(const bf16x8*)&Zl[w][(16 + m) * 72 + 32 + q * 8];

  unsigned k00 = ~0u, k01 = ~0u, k02 = ~0u, k03 = ~0u;
  unsigned k10 = ~0u, k11 = ~0u, k12 = ~0u, k13 = ~0u;

  // ---- stream all 512 codes: 32 tiles, 1-deep prefetch ---------------------
  const __bf16* Eb = E16 + m * 64 + q * 8;
  bf16x8 B0 = *(const bf16x8*)Eb;
  bf16x8 B1 = *(const bf16x8*)(Eb + 32);
  float  en = en2[m];
  #pragma unroll 4
  for (int ct = 0; ct < 32; ++ct) {
    bf16x8 nB0, nB1; float nen;
    if (ct < 31) {
      const __bf16* nb = Eb + (ct + 1) * 1024;
      nB0 = *(const bf16x8*)nb;
      nB1 = *(const bf16x8*)(nb + 32);
      nen = en2[(ct + 1) * 16 + m];
    }
    f32x4 einit = {en, en, en, en};
    const unsigned cvec = (unsigned)(ct * 16 + m);
    f32x4 a0 = __builtin_amdgcn_mfma_f32_16x16x32_bf16(A00, B0, einit, 0, 0, 0);
    a0 = __builtin_amdgcn_mfma_f32_16x16x32_bf16(A01, B1, a0, 0, 0, 0);
    f32x4 a1 = __builtin_amdgcn_mfma_f32_16x16x32_bf16(A10, B0, einit, 0, 0, 0);
    a1 = __builtin_amdgcn_mfma_f32_16x16x32_bf16(A11, B1, a1, 0, 0, 0);
    ARGMIN(k00, a0[0]) ARGMIN(k01, a0[1]) ARGMIN(k02, a0[2]) ARGMIN(k03, a0[3])
    ARGMIN(k10, a1[0]) ARGMIN(k11, a1[1]) ARGMIN(k12, a1[2]) ARGMIN(k13, a1[3])
    B0 = nB0; B1 = nB1; en = nen;
  }

  // ---- merge across the 16 column-lanes (codes) ----------------------------
  MERGE16(k00) MERGE16(k01) MERGE16(k02) MERGE16(k03)
  MERGE16(k10) MERGE16(k11) MERGE16(k12) MERGE16(k13)

  // winner px for (pt,q,r) = pt*16 + q*4 + r; lanes m==0 publish
  if (m == 0) {
    i32x4 w0, w1;
    w0[0] = (int)(k00 & 511u); w0[1] = (int)(k01 & 511u);
    w0[2] = (int)(k02 & 511u); w0[3] = (int)(k03 & 511u);
    w1[0] = (int)(k10 & 511u); w1[1] = (int)(k11 & 511u);
    w1[2] = (int)(k12 & 511u); w1[3] = (int)(k13 & 511u);
    *(i32x4*)&idxl[w][q * 4]      = w0;
    *(i32x4*)&idxl[w][16 + q * 4] = w1;
  }

  // ---- loss partial: |z|^2 partial per lane + min-dist (counted once, m==0)
  float ll = zn;
  if (m == 0) {
    ll += (__uint_as_float(k00) - 2.f) + (__uint_as_float(k01) - 2.f)
        + (__uint_as_float(k02) - 2.f) + (__uint_as_float(k03) - 2.f)
        + (__uint_as_float(k10) - 2.f) + (__uint_as_float(k11) - 2.f)
        + (__uint_as_float(k12) - 2.f) + (__uint_as_float(k13) - 2.f);
  }
  #pragma unroll
  for (int off = 1; off < 64; off <<= 1) ll += __shfl_xor(ll, off);
  if (lane == 0) cells[g] = ll;

  __threadfence_block();                  // idxl visible within the wave

  // ---- gather E[idx] fp32 + store: lane (q,m) -> px 2m,2m+1; d = q + 4j ----
  {
    int2 id2 = *(const int2*)&idxl[w][2 * m];
    const float* e0 = E + id2.x * 64;
    const float* e1 = E + id2.y * 64;
    float* op = out + 1 + base + 2 * m;
    #pragma unroll
    for (int j = 0; j < 16; ++j) {
      int d = q + 4 * j;
      f32x2u v; v[0] = e0[d]; v[1] = e1[d];
      *(f32x2u*)(op + d * 4096) = v;
    }
  }
}

// ---- tiny reduce: sum 4096 wave partials -> out[0] -------------------------
__global__ __launch_bounds__(256) void vq_loss(const float* __restrict__ cells,
                                               float* __restrict__ out) {
  __shared__ float wsum[4];
  int t = threadIdx.x;
  const float4* c4 = (const float4*)cells;         // 1024 float4
  float s = 0.f;
  #pragma unroll
  for (int j = 0; j < 4; ++j) {
    float4 v = c4[t + 256 * j];
    s += v.x + v.y + v.z + v.w;
  }
  #pragma unroll
  for (int off = 1; off < 64; off <<= 1) s += __shfl_xor(s, off);
  if ((t & 63) == 0) wsum[t >> 6] = s;
  __syncthreads();
  if (t == 0) out[0] = (wsum[0] + wsum[1] + wsum[2] + wsum[3]) * LOSS_SCALE;
}

extern "C" void kernel_launch(void* const* d_in, const int* in_sizes, int n_in,
                              void* d_out, int out_size, void* d_ws, size_t ws_size,
                              hipStream_t stream) {
  (void)in_sizes; (void)n_in; (void)out_size; (void)ws_size;
  const float* in = (const float*)d_in[0];   // [32,64,64,64]
  const float* E  = (const float*)d_in[1];   // [512,64]
  float* out = (float*)d_out;                // [1 + 8388608]
  __bf16* E16   = (__bf16*)d_ws;                       // 64 KiB
  float*  en2   = (float*)((char*)d_ws + 65536);       // 2 KiB
  float*  cells = (float*)((char*)d_ws + 67584);       // 16 KiB

  vq_prep<<<32, 256, 0, stream>>>(E, E16, en2);
  vq_main<<<1024, 256, 0, stream>>>(in, E, E16, en2, out, cells);
  vq_loss<<<1, 256, 0, stream>>>(cells, out);
}

// Round 6
// 105.257 us; speedup vs baseline: 2.4271x; 1.2255x over previous
//
#include <hip/hip_runtime.h>

// VectorQuantizer: B=32,D=64,H=64,W=64 -> N=131072 px; K=512 codes.
// out[0] = 1.25*mean((E[idx]-z)^2); out[1..] = Zq as [B,D,H,W].
// R5: R4's barrier-free wave-per-32px skeleton, but with memory-transaction
// (segment) counts collapsed:
//  - E16s pre-swizzled to MFMA fragment order: B-tile load = 16 B/lane
//    contiguous (1 KiB/instr, 1 coalesce group vs 16).
//  - Zq gather: cooperative row fetch (16 lanes x float4 = 1 row; 4 rows/instr
//    = 4 segments vs 64) into per-wave LDS transpose zqT[64][33], then
//    px-contiguous stores from LDS.
// dist = en2 + (-2z).e via MFMA C operand, in (1,3) => raw uint bits are
// order-monotone; low 9 bits carry code idx. Loss -> cells -> tiny reducer.

typedef __bf16 bf16x8 __attribute__((ext_vector_type(8)));
typedef float  f32x4  __attribute__((ext_vector_type(4)));
typedef int    i32x4  __attribute__((ext_vector_type(4)));

#define LOSS_SCALE (1.25f / 8388608.f)   // 1.25 / (N*D)

// ---- prep: E fp32 -> E16s (fragment-major bf16) + en2s ---------------------
// E16s (bf16 units): [((ct*2 + half)*64 + lane) * 8 + j]
//   for lane=(q=lane>>4, m=lane&15): code c = ct*16+m, dim = half*32 + q*8 + j
// en2s[ct*64 + lane] = |E[ct*16 + (lane&15)]|^2 + 2
__global__ __launch_bounds__(256) void vq_prep(const float* __restrict__ E,
                                               __bf16* __restrict__ E16s,
                                               float* __restrict__ en2s) {
  int tau = blockIdx.x * 256 + threadIdx.x;        // 4096 threads
  int lane = tau & 63, half = (tau >> 6) & 1, ct = tau >> 7;
  int m = lane & 15, q = lane >> 4;
  int c = ct * 16 + m;
  const float* src = E + c * 64 + half * 32 + q * 8;
  float4 s0 = *(const float4*)src;
  float4 s1 = *(const float4*)(src + 4);
  bf16x8 b;
  b[0] = (__bf16)s0.x; b[1] = (__bf16)s0.y; b[2] = (__bf16)s0.z; b[3] = (__bf16)s0.w;
  b[4] = (__bf16)s1.x; b[5] = (__bf16)s1.y; b[6] = (__bf16)s1.z; b[7] = (__bf16)s1.w;
  *(bf16x8*)(E16s + tau * 8) = b;
  if (half == 0) {                                 // redundant x16 but tiny
    const float4* row = (const float4*)(E + c * 64);
    float ss = 0.f;
    #pragma unroll
    for (int i = 0; i < 16; ++i) {
      float4 v = row[i];
      ss += v.x * v.x + v.y * v.y + v.z * v.z + v.w * v.w;
    }
    en2s[ct * 64 + lane] = ss + 2.0f;
  }
}

#define ARGMIN(KK, RV) { unsigned key_ = (__float_as_uint(RV) & 0xFFFFFE00u) | cvec; \
                         if (key_ < KK) KK = key_; }
#define MERGE16(KK) { unsigned o_; \
    o_ = __shfl_xor(KK, 1); if (o_ < KK) KK = o_; \
    o_ = __shfl_xor(KK, 2); if (o_ < KK) KK = o_; \
    o_ = __shfl_xor(KK, 4); if (o_ < KK) KK = o_; \
    o_ = __shfl_xor(KK, 8); if (o_ < KK) KK = o_; }

__global__ __launch_bounds__(256, 4) void vq_main(const float* __restrict__ in,
                                                  const float* __restrict__ E,
                                                  const __bf16* __restrict__ E16s,
                                                  const float* __restrict__ en2s,
                                                  float* __restrict__ out,
                                                  float* __restrict__ cells) {
  // per-wave arena: staging tile (bf16, 32px x 72) OR fp32 transpose zqT[64][33]
  struct Arena { union { __bf16 z[2304]; float zq[2112]; } u; };
  __shared__ Arena ar[4];
  __shared__ int idxl[4][32];

  const int t = threadIdx.x, lane = t & 63, w = t >> 6;
  const int q = lane >> 4, m = lane & 15;
  const int g = blockIdx.x * 4 + w;                 // wave tile 0..4095 (32 px)
  const int base = (g >> 7) * 262144 + ((g & 127) << 5);

  // ---- stage: lane loads 16 float2 (px 2m,2m+1) at d = q*16+j --------------
  float zn = 0.f;
  {
    float2 L[16];
    const float* p = in + base + (q * 16) * 4096 + 2 * m;
    #pragma unroll
    for (int j = 0; j < 16; ++j) L[j] = *(const float2*)(p + j * 4096);
    bf16x8 c00, c01, c10, c11;
    #pragma unroll
    for (int j = 0; j < 8; ++j) {
      c00[j] = (__bf16)(-2.f * L[j].x);
      c10[j] = (__bf16)(-2.f * L[j].y);
      c01[j] = (__bf16)(-2.f * L[j + 8].x);
      c11[j] = (__bf16)(-2.f * L[j + 8].y);
    }
    #pragma unroll
    for (int j = 0; j < 16; ++j) zn += L[j].x * L[j].x + L[j].y * L[j].y;
    __bf16* r0 = &ar[w].u.z[(2 * m) * 72 + q * 16];
    __bf16* r1 = &ar[w].u.z[(2 * m + 1) * 72 + q * 16];
    *(bf16x8*)r0 = c00; *(bf16x8*)(r0 + 8) = c01;
    *(bf16x8*)r1 = c10; *(bf16x8*)(r1 + 8) = c11;
  }
  __threadfence_block();                  // wave-local LDS visibility

  // ---- A fragments: px = pt*16 + m, k-halves q*8 / 32+q*8 ------------------
  bf16x8 A00 = *(const bf16x8*)&ar[w].u.z[(m) * 72 + q * 8];
  bf16x8 A01 = *(const bf16x8*)&ar[w].u.z[(m) * 72 + 32 + q * 8];
  bf16x8 A10 = *(const bf16x8*)&ar[w].u.z[(16 + m) * 72 + q * 8];
  bf16x8 A11 = *(const bf16x8*)&ar[w].u.z[(16 + m) * 72 + 32 + q * 8];

  unsigned k00 = ~0u, k01 = ~0u, k02 = ~0u, k03 = ~0u;
  unsigned k10 = ~0u, k11 = ~0u, k12 = ~0u, k13 = ~0u;

  // ---- stream all 512 codes: 32 tiles, fully coalesced frag loads ----------
  const __bf16* Eb = E16s + lane * 8;     // + ct*1024 (+512 for B1)
  bf16x8 B0 = *(const bf16x8*)Eb;
  bf16x8 B1 = *(const bf16x8*)(Eb + 512);
  float  en = en2s[lane];
  #pragma unroll 4
  for (int ct = 0; ct < 32; ++ct) {
    bf16x8 nB0, nB1; float nen;
    if (ct < 31) {
      const __bf16* nb = Eb + (ct + 1) * 1024;
      nB0 = *(const bf16x8*)nb;
      nB1 = *(const bf16x8*)(nb + 512);
      nen = en2s[(ct + 1) * 64 + lane];
    }
    f32x4 einit = {en, en, en, en};
    const unsigned cvec = (unsigned)(ct * 16 + m);
    f32x4 a0 = __builtin_amdgcn_mfma_f32_16x16x32_bf16(A00, B0, einit, 0, 0, 0);
    a0 = __builtin_amdgcn_mfma_f32_16x16x32_bf16(A01, B1, a0, 0, 0, 0);
    f32x4 a1 = __builtin_amdgcn_mfma_f32_16x16x32_bf16(A10, B0, einit, 0, 0, 0);
    a1 = __builtin_amdgcn_mfma_f32_16x16x32_bf16(A11, B1, a1, 0, 0, 0);
    ARGMIN(k00, a0[0]) ARGMIN(k01, a0[1]) ARGMIN(k02, a0[2]) ARGMIN(k03, a0[3])
    ARGMIN(k10, a1[0]) ARGMIN(k11, a1[1]) ARGMIN(k12, a1[2]) ARGMIN(k13, a1[3])
    B0 = nB0; B1 = nB1; en = nen;
  }

  // ---- merge across the 16 code-column lanes -------------------------------
  MERGE16(k00) MERGE16(k01) MERGE16(k02) MERGE16(k03)
  MERGE16(k10) MERGE16(k11) MERGE16(k12) MERGE16(k13)

  if (m == 0) {                           // publish winners: px = pt*16+q*4+r
    i32x4 w0, w1;
    w0[0] = (int)(k00 & 511u); w0[1] = (int)(k01 & 511u);
    w0[2] = (int)(k02 & 511u); w0[3] = (int)(k03 & 511u);
    w1[0] = (int)(k10 & 511u); w1[1] = (int)(k11 & 511u);
    w1[2] = (int)(k12 & 511u); w1[3] = (int)(k13 & 511u);
    *(i32x4*)&idxl[w][q * 4]      = w0;
    *(i32x4*)&idxl[w][16 + q * 4] = w1;
  }

  // ---- loss partial --------------------------------------------------------
  float ll = zn;
  if (m == 0) {
    ll += (__uint_as_float(k00) - 2.f) + (__uint_as_float(k01) - 2.f)
        + (__uint_as_float(k02) - 2.f) + (__uint_as_float(k03) - 2.f)
        + (__uint_as_float(k10) - 2.f) + (__uint_as_float(k11) - 2.f)
        + (__uint_as_float(k12) - 2.f) + (__uint_as_float(k13) - 2.f);
  }
  #pragma unroll
  for (int off = 1; off < 64; off <<= 1) ll += __shfl_xor(ll, off);
  if (lane == 0) cells[g] = ll;

  __threadfence_block();                  // idxl visible within the wave

  // ---- cooperative gather: 16 lanes fetch one row; 4 rows/instr ------------
  // j-th step: px p = j*4 + q; lane fetches dims 4m..4m+3 -> zqT[d][p]
  float* zqT = ar[w].u.zq;                // [64][33]
  #pragma unroll
  for (int j = 0; j < 8; ++j) {
    int p = j * 4 + q;
    int row = idxl[w][p];
    float4 v = *(const float4*)(E + row * 64 + m * 4);
    zqT[(4 * m + 0) * 33 + p] = v.x;
    zqT[(4 * m + 1) * 33 + p] = v.y;
    zqT[(4 * m + 2) * 33 + p] = v.z;
    zqT[(4 * m + 3) * 33 + p] = v.w;
  }
  __threadfence_block();

  // ---- store: lane (q,m) -> d = j*4+q, px 2m,2m+1 (4x128B segs/instr) ------
  {
    float* op = out + 1 + base + 2 * m;
    #pragma unroll
    for (int j = 0; j < 16; ++j) {
      int d = j * 4 + q;
      float f0 = zqT[d * 33 + 2 * m];
      float f1 = zqT[d * 33 + 2 * m + 1];
      op[d * 4096]     = f0;
      op[d * 4096 + 1] = f1;
    }
  }
}

// ---- tiny reduce: sum 4096 wave partials -> out[0] -------------------------
__global__ __launch_bounds__(256) void vq_loss(const float* __restrict__ cells,
                                               float* __restrict__ out) {
  __shared__ float wsum[4];
  int t = threadIdx.x;
  const float4* c4 = (const float4*)cells;         // 1024 float4
  float s = 0.f;
  #pragma unroll
  for (int j = 0; j < 4; ++j) {
    float4 v = c4[t + 256 * j];
    s += v.x + v.y + v.z + v.w;
  }
  #pragma unroll
  for (int off = 1; off < 64; off <<= 1) s += __shfl_xor(s, off);
  if ((t & 63) == 0) wsum[t >> 6] = s;
  __syncthreads();
  if (t == 0) out[0] = (wsum[0] + wsum[1] + wsum[2] + wsum[3]) * LOSS_SCALE;
}

extern "C" void kernel_launch(void* const* d_in, const int* in_sizes, int n_in,
                              void* d_out, int out_size, void* d_ws, size_t ws_size,
                              hipStream_t stream) {
  (void)in_sizes; (void)n_in; (void)out_size; (void)ws_size;
  const float* in = (const float*)d_in[0];   // [32,64,64,64]
  const float* E  = (const float*)d_in[1];   // [512,64]
  float* out = (float*)d_out;                // [1 + 8388608]
  __bf16* E16s  = (__bf16*)d_ws;                       // 64 KiB
  float*  en2s  = (float*)((char*)d_ws + 65536);       // 8 KiB
  float*  cells = (float*)((char*)d_ws + 73728);       // 16 KiB

  vq_prep<<<16, 256, 0, stream>>>(E, E16s, en2s);
  vq_main<<<1024, 256, 0, stream>>>(in, E, E16s, en2s, out, cells);
  vq_loss<<<1, 256, 0, stream>>>(cells, out);
}

// Round 7
// 97.192 us; speedup vs baseline: 2.6285x; 1.0830x over previous
//
#include <hip/hip_runtime.h>

// VectorQuantizer: B=32,D=64,H=64,W=64 -> N=131072 px; K=512 codes.
// out[0] = 1.25*mean((E[idx]-z)^2); out[1..] = Zq as [B,D,H,W].
// R6 = R5 (barrier-free wave-per-32px; fragment-major E16s so every B load is
// 16B/lane fully coalesced; cooperative gather via LDS transpose) + DEPTH-4
// B-prefetch ring (R5's 1-deep prefetch left ~150 cyc vmcnt stall per tile:
// load->use distance ~50cyc vs ~200cyc L2 latency). Ring arrays are indexed
// by constants after full unroll -> guaranteed VGPRs, no scratch.
// dist = en2 + (-2z).e via MFMA C operand, in (1,3) => raw uint bits are
// order-monotone; low 9 bits carry code idx. Loss -> cells -> tiny reducer.

typedef __bf16 bf16x8 __attribute__((ext_vector_type(8)));
typedef float  f32x4  __attribute__((ext_vector_type(4)));
typedef int    i32x4  __attribute__((ext_vector_type(4)));
typedef float  f32x2u __attribute__((ext_vector_type(2), aligned(4)));

#define LOSS_SCALE (1.25f / 8388608.f)   // 1.25 / (N*D)

// ---- prep: E fp32 -> E16s (fragment-major bf16) + en2s ---------------------
// E16s (bf16 units): [((ct*2 + half)*64 + lane) * 8 + j]
//   lane=(q=lane>>4, m=lane&15): code c = ct*16+m, dim = half*32 + q*8 + j
// en2s[ct*64 + lane] = |E[ct*16 + (lane&15)]|^2 + 2
__global__ __launch_bounds__(256) void vq_prep(const float* __restrict__ E,
                                               __bf16* __restrict__ E16s,
                                               float* __restrict__ en2s) {
  int tau = blockIdx.x * 256 + threadIdx.x;        // 4096 threads
  int lane = tau & 63, half = (tau >> 6) & 1, ct = tau >> 7;
  int m = lane & 15, q = lane >> 4;
  int c = ct * 16 + m;
  const float* src = E + c * 64 + half * 32 + q * 8;
  float4 s0 = *(const float4*)src;
  float4 s1 = *(const float4*)(src + 4);
  bf16x8 b;
  b[0] = (__bf16)s0.x; b[1] = (__bf16)s0.y; b[2] = (__bf16)s0.z; b[3] = (__bf16)s0.w;
  b[4] = (__bf16)s1.x; b[5] = (__bf16)s1.y; b[6] = (__bf16)s1.z; b[7] = (__bf16)s1.w;
  *(bf16x8*)(E16s + tau * 8) = b;
  if (half == 0) {                                 // redundant x16 but tiny
    const float4* row = (const float4*)(E + c * 64);
    float ss = 0.f;
    #pragma unroll
    for (int i = 0; i < 16; ++i) {
      float4 v = row[i];
      ss += v.x * v.x + v.y * v.y + v.z * v.z + v.w * v.w;
    }
    en2s[ct * 64 + lane] = ss + 2.0f;
  }
}

#define ARGMIN(KK, RV) { unsigned key_ = (__float_as_uint(RV) & 0xFFFFFE00u) | cvec; \
                         if (key_ < KK) KK = key_; }
#define MERGE16(KK) { unsigned o_; \
    o_ = __shfl_xor(KK, 1); if (o_ < KK) KK = o_; \
    o_ = __shfl_xor(KK, 2); if (o_ < KK) KK = o_; \
    o_ = __shfl_xor(KK, 4); if (o_ < KK) KK = o_; \
    o_ = __shfl_xor(KK, 8); if (o_ < KK) KK = o_; }

__global__ __launch_bounds__(256, 4) void vq_main(const float* __restrict__ in,
                                                  const float* __restrict__ E,
                                                  const __bf16* __restrict__ E16s,
                                                  const float* __restrict__ en2s,
                                                  float* __restrict__ out,
                                                  float* __restrict__ cells) {
  // per-wave arena: staging tile (bf16, 32px x 72) OR fp32 transpose zqT[64][33]
  struct Arena { union { __bf16 z[2304]; float zq[2112]; } u; };
  __shared__ Arena ar[4];
  __shared__ int idxl[4][32];

  const int t = threadIdx.x, lane = t & 63, w = t >> 6;
  const int q = lane >> 4, m = lane & 15;
  const int g = blockIdx.x * 4 + w;                 // wave tile 0..4095 (32 px)
  const int base = (g >> 7) * 262144 + ((g & 127) << 5);

  // ---- stage: lane loads 16 float2 (px 2m,2m+1) at d = q*16+j --------------
  float zn = 0.f;
  {
    float2 L[16];
    const float* p = in + base + (q * 16) * 4096 + 2 * m;
    #pragma unroll
    for (int j = 0; j < 16; ++j) L[j] = *(const float2*)(p + j * 4096);
    bf16x8 c00, c01, c10, c11;
    #pragma unroll
    for (int j = 0; j < 8; ++j) {
      c00[j] = (__bf16)(-2.f * L[j].x);
      c10[j] = (__bf16)(-2.f * L[j].y);
      c01[j] = (__bf16)(-2.f * L[j + 8].x);
      c11[j] = (__bf16)(-2.f * L[j + 8].y);
    }
    #pragma unroll
    for (int j = 0; j < 16; ++j) zn += L[j].x * L[j].x + L[j].y * L[j].y;
    __bf16* r0 = &ar[w].u.z[(2 * m) * 72 + q * 16];
    __bf16* r1 = &ar[w].u.z[(2 * m + 1) * 72 + q * 16];
    *(bf16x8*)r0 = c00; *(bf16x8*)(r0 + 8) = c01;
    *(bf16x8*)r1 = c10; *(bf16x8*)(r1 + 8) = c11;
  }
  __threadfence_block();                  // wave-local LDS visibility

  // ---- A fragments: px = pt*16 + m, k-halves q*8 / 32+q*8 ------------------
  bf16x8 A00 = *(const bf16x8*)&ar[w].u.z[(m) * 72 + q * 8];
  bf16x8 A01 = *(const bf16x8*)&ar[w].u.z[(m) * 72 + 32 + q * 8];
  bf16x8 A10 = *(const bf16x8*)&ar[w].u.z[(16 + m) * 72 + q * 8];
  bf16x8 A11 = *(const bf16x8*)&ar[w].u.z[(16 + m) * 72 + 32 + q * 8];

  unsigned k00 = ~0u, k01 = ~0u, k02 = ~0u, k03 = ~0u;
  unsigned k10 = ~0u, k11 = ~0u, k12 = ~0u, k13 = ~0u;

  // ---- stream all 512 codes: 32 tiles, depth-4 prefetch ring ---------------
  const __bf16* Eb = E16s + lane * 8;     // + ct*1024 (+512 for B1)
  bf16x8 P0[4], P1[4];
  float  PE[4];
  #pragma unroll
  for (int i = 0; i < 4; ++i) {
    P0[i] = *(const bf16x8*)(Eb + i * 1024);
    P1[i] = *(const bf16x8*)(Eb + i * 1024 + 512);
    PE[i] = en2s[i * 64 + lane];
  }
  #pragma unroll
  for (int ct = 0; ct < 32; ++ct) {
    const int s = ct & 3;
    bf16x8 B0 = P0[s], B1 = P1[s];
    float  en = PE[s];
    {                                     // refill slot with tile ct+4 (clamped)
      int nt = ct + 4; nt = nt > 31 ? 31 : nt;
      P0[s] = *(const bf16x8*)(Eb + nt * 1024);
      P1[s] = *(const bf16x8*)(Eb + nt * 1024 + 512);
      PE[s] = en2s[nt * 64 + lane];
    }
    f32x4 einit = {en, en, en, en};
    const unsigned cvec = (unsigned)(ct * 16 + m);
    f32x4 a0 = __builtin_amdgcn_mfma_f32_16x16x32_bf16(A00, B0, einit, 0, 0, 0);
    a0 = __builtin_amdgcn_mfma_f32_16x16x32_bf16(A01, B1, a0, 0, 0, 0);
    f32x4 a1 = __builtin_amdgcn_mfma_f32_16x16x32_bf16(A10, B0, einit, 0, 0, 0);
    a1 = __builtin_amdgcn_mfma_f32_16x16x32_bf16(A11, B1, a1, 0, 0, 0);
    ARGMIN(k00, a0[0]) ARGMIN(k01, a0[1]) ARGMIN(k02, a0[2]) ARGMIN(k03, a0[3])
    ARGMIN(k10, a1[0]) ARGMIN(k11, a1[1]) ARGMIN(k12, a1[2]) ARGMIN(k13, a1[3])
  }

  // ---- merge across the 16 code-column lanes -------------------------------
  MERGE16(k00) MERGE16(k01) MERGE16(k02) MERGE16(k03)
  MERGE16(k10) MERGE16(k11) MERGE16(k12) MERGE16(k13)

  if (m == 0) {                           // publish winners: px = pt*16+q*4+r
    i32x4 w0, w1;
    w0[0] = (int)(k00 & 511u); w0[1] = (int)(k01 & 511u);
    w0[2] = (int)(k02 & 511u); w0[3] = (int)(k03 & 511u);
    w1[0] = (int)(k10 & 511u); w1[1] = (int)(k11 & 511u);
    w1[2] = (int)(k12 & 511u); w1[3] = (int)(k13 & 511u);
    *(i32x4*)&idxl[w][q * 4]      = w0;
    *(i32x4*)&idxl[w][16 + q * 4] = w1;
  }

  // ---- loss partial --------------------------------------------------------
  float ll = zn;
  if (m == 0) {
    ll += (__uint_as_float(k00) - 2.f) + (__uint_as_float(k01) - 2.f)
        + (__uint_as_float(k02) - 2.f) + (__uint_as_float(k03) - 2.f)
        + (__uint_as_float(k10) - 2.f) + (__uint_as_float(k11) - 2.f)
        + (__uint_as_float(k12) - 2.f) + (__uint_as_float(k13) - 2.f);
  }
  #pragma unroll
  for (int off = 1; off < 64; off <<= 1) ll += __shfl_xor(ll, off);
  if (lane == 0) cells[g] = ll;

  __threadfence_block();                  // idxl visible within the wave

  // ---- cooperative gather: 16 lanes fetch one row; 4 rows/instr ------------
  // j-th step: px p = j*4 + q; lane fetches dims 4m..4m+3 -> zqT[d][p]
  float* zqT = ar[w].u.zq;                // [64][33]
  #pragma unroll
  for (int j = 0; j < 8; ++j) {
    int p = j * 4 + q;
    int row = idxl[w][p];
    float4 v = *(const float4*)(E + row * 64 + m * 4);
    zqT[(4 * m + 0) * 33 + p] = v.x;
    zqT[(4 * m + 1) * 33 + p] = v.y;
    zqT[(4 * m + 2) * 33 + p] = v.z;
    zqT[(4 * m + 3) * 33 + p] = v.w;
  }
  __threadfence_block();

  // ---- store: lane (q,m) -> d = j*4+q, px 2m,2m+1 (dwordx2, 128B/q-seg) ----
  {
    float* op = out + 1 + base + 2 * m;
    #pragma unroll
    for (int j = 0; j < 16; ++j) {
      int d = j * 4 + q;
      f32x2u v;
      v[0] = zqT[d * 33 + 2 * m];
      v[1] = zqT[d * 33 + 2 * m + 1];
      *(f32x2u*)(op + d * 4096) = v;
    }
  }
}

// ---- tiny reduce: sum 4096 wave partials -> out[0] -------------------------
__global__ __launch_bounds__(256) void vq_loss(const float* __restrict__ cells,
                                               float* __restrict__ out) {
  __shared__ float wsum[4];
  int t = threadIdx.x;
  const float4* c4 = (const float4*)cells;         // 1024 float4
  float s = 0.f;
  #pragma unroll
  for (int j = 0; j < 4; ++j) {
    float4 v = c4[t + 256 * j];
    s += v.x + v.y + v.z + v.w;
  }
  #pragma unroll
  for (int off = 1; off < 64; off <<= 1) s += __shfl_xor(s, off);
  if ((t & 63) == 0) wsum[t >> 6] = s;
  __syncthreads();
  if (t == 0) out[0] = (wsum[0] + wsum[1] + wsum[2] + wsum[3]) * LOSS_SCALE;
}

extern "C" void kernel_launch(void* const* d_in, const int* in_sizes, int n_in,
                              void* d_out, int out_size, void* d_ws, size_t ws_size,
                              hipStream_t stream) {
  (void)in_sizes; (void)n_in; (void)out_size; (void)ws_size;
  const float* in = (const float*)d_in[0];   // [32,64,64,64]
  const float* E  = (const float*)d_in[1];   // [512,64]
  float* out = (float*)d_out;                // [1 + 8388608]
  __bf16* E16s  = (__bf16*)d_ws;                       // 64 KiB
  float*  en2s  = (float*)((char*)d_ws + 65536);       // 8 KiB
  float*  cells = (float*)((char*)d_ws + 73728);       // 16 KiB

  vq_prep<<<16, 256, 0, stream>>>(E, E16s, en2s);
  vq_main<<<1024, 256, 0, stream>>>(in, E, E16s, en2s, out, cells);
  vq_loss<<<1, 256, 0, stream>>>(cells, out);
}